// Round 18
// baseline (62.358 us; speedup 1.0000x reference)
//
#include <hip/hip_runtime.h>
#include <hip/hip_bf16.h>

typedef __attribute__((ext_vector_type(8))) short short8;
typedef __attribute__((ext_vector_type(8))) _Float16 half8;
typedef __attribute__((ext_vector_type(2))) _Float16 h2;
typedef __attribute__((ext_vector_type(4))) float f32x4;
typedef __attribute__((ext_vector_type(4))) unsigned uintx4;

#define NFACE 16384
#define NBATCH 8
#define CIN 128
#define COUT 128
#define KGEMM 512
#define MBLK 128                       // faces per block (4 iters of 32)
#define GRID ((NBATCH * NFACE) / MBLK) // 1024, divisible by 8
#define LDA 520                        // A row stride in halfs (512 + 8) — R15 proven
#define FCONV_BLOCKS 8192              // feature-convert blocks (exact, no bound check)
#define NROW (NBATCH * NFACE)          // 131072 output rows
#define ZBM_WORDS (NROW / 32)          // 4096 words = 16 KiB zero-bitmap

__device__ __forceinline__ unsigned short f2bf(float x) {
    union { float f; unsigned u; } v; v.f = x;
    unsigned r = v.u + 0x7fffu + ((v.u >> 16) & 1u);  // RNE
    return (unsigned short)(r >> 16);
}
__device__ __forceinline__ unsigned pack2bf(float lo, float hi) {
    return (unsigned)f2bf(lo) | ((unsigned)f2bf(hi) << 16);
}
__device__ __forceinline__ h2 habs2(h2 x) {
    union { h2 h; unsigned u; } v; v.h = x; v.u &= 0x7fff7fffu; return v.h;
}
__device__ __forceinline__ unsigned h2u(h2 x) {
    union { h2 h; unsigned u; } v; v.h = x; return v.u;
}
__device__ __forceinline__ h2 u2h(unsigned x) {
    union { h2 h; unsigned u; } v; v.u = x; return v.h;
}

// ---- fused prep: features fp32 -> f16 (blocks < 8192), weight fp32 -> f16
// kk-major (next 64 blocks), zero-row bitmap (last block — single block so the
// zero->set ordering is safe within one __syncthreads).
__global__ void prep_kernel(const float* __restrict__ f, unsigned* __restrict__ o,
                            const float* __restrict__ w, _Float16* __restrict__ bt,
                            const int* __restrict__ zm, const int* __restrict__ zf,
                            unsigned* __restrict__ zbm, int wblocks) {
    const int b = blockIdx.x;
    if (b < FCONV_BLOCKS) {
        const int i = b * 256 + threadIdx.x;  // one uint4 (8 floats -> 8 halfs)
        const float4* fp = (const float4*)f;
        float4 a = fp[i * 2], c = fp[i * 2 + 1];
        h2 p0 = {(_Float16)a.x, (_Float16)a.y};
        h2 p1 = {(_Float16)a.z, (_Float16)a.w};
        h2 p2 = {(_Float16)c.x, (_Float16)c.y};
        h2 p3 = {(_Float16)c.z, (_Float16)c.w};
        uint4 r; r.x = h2u(p0); r.y = h2u(p1); r.z = h2u(p2); r.w = h2u(p3);
        ((uint4*)o)[i] = r;
    } else if (b < FCONV_BLOCKS + wblocks) {
        const int i = (b - FCONV_BLOCKS) * 256 + threadIdx.x;  // one (o,c) pair
        if (i >= COUT * CIN) return;
        int oo = i >> 7, c = i & 127;
        float4 wv = ((const float4*)w)[i];
        _Float16* dst = bt + (size_t)oo * KGEMM + c;   // wbth[o][kk*128 + c]
        dst[0]   = (_Float16)wv.x;
        dst[128] = (_Float16)wv.y;
        dst[256] = (_Float16)wv.z;
        dst[384] = (_Float16)wv.w;
    } else {
        // zero-bitmap: clear 4096 words, sync, set 1024 bits (atomicOr, dup-safe)
        const int t = threadIdx.x;
        for (int i = t; i < ZBM_WORDS; i += 256) zbm[i] = 0u;
        __syncthreads();
        for (int i = t; i < 1024; i += 256) {
            const unsigned row = (unsigned)zm[i] * NFACE + (unsigned)zf[i];
            atomicOr(&zbm[row >> 5], 1u << (row & 31));
        }
    }
}

// ---- old-layout bf16 weight (fallback path): bt[o][kk*128+c] ----
__global__ void wconv_kernel(const float* __restrict__ w, unsigned short* __restrict__ bt) {
    int i = blockIdx.x * 256 + threadIdx.x;
    if (i >= COUT * CIN) return;
    int o = i >> 7, c = i & 127;
#pragma unroll
    for (int kk = 0; kk < 4; ++kk)
        bt[o * KGEMM + kk * CIN + c] = f2bf(w[(o * CIN + c) * 4 + kk]);
}

// Compute fcv from 6 gathered row-segments and write the 4 kk-major A slices.
// (Consume-side of the T14 split — the loads were issued BEFORE the GEMM.)
__device__ __forceinline__ void build_compute(const uint4 n[6], int oct,
                                              _Float16* __restrict__ Arow) {
    unsigned f1w[4], f2w[4], f3w[4];
#pragma unroll
    for (int q = 0; q < 4; ++q) {  // q = word = channels 2q,2q+1
        h2 x0 = u2h(((const unsigned*)&n[0])[q]);
        h2 x1 = u2h(((const unsigned*)&n[1])[q]);
        h2 x2 = u2h(((const unsigned*)&n[2])[q]);
        h2 x3 = u2h(((const unsigned*)&n[3])[q]);
        h2 x4 = u2h(((const unsigned*)&n[4])[q]);
        h2 x5 = u2h(((const unsigned*)&n[5])[q]);
        h2 s = x1 + x2; s = s + x3; s = s + x4; s = s + x5;
        h2 five = {(_Float16)5.0f, (_Float16)5.0f};
        h2 d = habs2(five * x0 - s);
        h2 t3 = habs2(x1 - x2) + habs2(x1 - x3);
        t3 = t3 + habs2(x1 - x4); t3 = t3 + habs2(x1 - x5);
        t3 = t3 + habs2(x2 - x3); t3 = t3 + habs2(x2 - x4);
        t3 = t3 + habs2(x2 - x5); t3 = t3 + habs2(x3 - x4);
        t3 = t3 + habs2(x3 - x5); t3 = t3 + habs2(x4 - x5);
        f1w[q] = h2u(s); f2w[q] = h2u(d); f3w[q] = h2u(t3);
    }
    // A-row layout: halfs [kk*128 + c], c = oct*8 .. +8
    *(uint4*)&Arow[0 * 128 + oct * 8] = n[0];
    *(uint4*)&Arow[1 * 128 + oct * 8] = (uint4){f1w[0], f1w[1], f1w[2], f1w[3]};
    *(uint4*)&Arow[2 * 128 + oct * 8] = (uint4){f2w[0], f2w[1], f2w[2], f2w[3]};
    *(uint4*)&Arow[3 * 128 + oct * 8] = (uint4){f3w[0], f3w[1], f3w[2], f3w[3]};
}

// v18 = R17 (T14 split, pinned 16-col B, +8-pad LDS, setprio) + fused zero:
// epilogue masks rows via the bitmap (one SCALAR word per iter — all 32 rows of
// an iter share one word since base%128==0) -> zero_kernel launch removed.
__global__ __launch_bounds__(512, 4)
void meshconv_v18(const unsigned* __restrict__ featf16,
                  const int* __restrict__ ring,
                  const _Float16* __restrict__ wbth,
                  const float* __restrict__ bias,
                  const unsigned* __restrict__ zbm,
                  float* __restrict__ out)
{
    __shared__ _Float16 Abuf[2][32 * LDA];  // 2 x 32.5 KiB
    __shared__ int ridx[MBLK * 6];          // 3 KiB

    const int t = threadIdx.x;
    // batch-per-XCD swizzle (meshconv-side only — proven good since R4)
    const int bid = (blockIdx.x & 7) * (GRID / 8) + (blockIdx.x >> 3);
    const int base = bid * MBLK;
    const int batch = bid >> 7;

    if (t < 192)  // 128 faces * 6 ints = 192 uint4
        ((uint4*)ridx)[t] = ((const uint4*)(ring + (size_t)base * 6))[t];

    // GEMM mapping: 8 waves x 16 cols each
    const int w  = t >> 6;
    const int l  = t & 63;
    const int lo = l & 15;
    const int hi = l >> 4;
    const int col0 = w * 16;

    // ---- B preload: full K for this wave's 16 cols, once (L2), then PIN ----
    uintx4 B[16];
    {
        const _Float16* wb = wbth + (size_t)(col0 + lo) * KGEMM + hi * 8;
#pragma unroll
        for (int ks = 0; ks < 16; ++ks)
            B[ks] = *(const uintx4*)&wb[ks * 32];
    }
#pragma unroll
    for (int ks = 0; ks < 16; ++ks)
        asm volatile("" : "+v"(B[ks]));   // keep B on-chip (VGPR/AGPR)

    const float bo = bias[col0 + lo];

    // build mapping: thread = (face bf = t>>4 within 32, channel-octet oct = t&15)
    const int bf  = t >> 4;
    const int oct = t & 15;
    const char* __restrict__ fbb = (const char*)featf16 + (size_t)batch * NFACE * 256;

    __syncthreads();  // ridx ready

    // prologue: tile 0 built in place
    {
        uint4 n[6];
        const int* ri = &ridx[bf * 6];
#pragma unroll
        for (int j = 0; j < 6; ++j)
            n[j] = *(const uint4*)(fbb + (size_t)(ri[j] * 256 + oct * 16));
        build_compute(n, oct, &Abuf[0][bf * LDA]);
    }
    __syncthreads();

    for (int i = 0; i < 4; ++i) {
        // ---- phase 1: ISSUE next tile's gathers (held across GEMM) ----
        uint4 n[6];
        if (i < 3) {
            const int* ri = &ridx[((i + 1) * 32 + bf) * 6];
#pragma unroll
            for (int j = 0; j < 6; ++j)
                n[j] = *(const uint4*)(fbb + (size_t)(ri[j] * 256 + oct * 16));
        }
        __builtin_amdgcn_sched_barrier(0);  // loads stay issued here

        // ---- phase 2: GEMM on Abuf[i&1] (hides gather latency), T5 setprio ----
        f32x4 acc0 = (f32x4){0.f, 0.f, 0.f, 0.f};
        f32x4 acc1 = (f32x4){0.f, 0.f, 0.f, 0.f};
        const _Float16* __restrict__ Ab = &Abuf[i & 1][0];
        __builtin_amdgcn_s_setprio(1);
#pragma unroll
        for (int ks = 0; ks < 16; ++ks) {
            const int k0 = ks * 32 + hi * 8;
            half8 a0 = *(const half8*)&Ab[lo * LDA + k0];
            half8 a1 = *(const half8*)&Ab[(16 + lo) * LDA + k0];
            half8 b = __builtin_bit_cast(half8, B[ks]);
            acc0 = __builtin_amdgcn_mfma_f32_16x16x32_f16(a0, b, acc0, 0, 0, 0);
            acc1 = __builtin_amdgcn_mfma_f32_16x16x32_f16(a1, b, acc1, 0, 0, 0);
        }
        __builtin_amdgcn_s_setprio(0);

        // zero-row mask: rows [base+i*32, +32) share one bitmap word (base%128==0)
        const unsigned zmask = zbm[(unsigned)(base + i * 32) >> 5];
#pragma unroll
        for (int v = 0; v < 4; ++v) {
            const int rr = i * 32 + hi * 4 + v;              // row within block-iter
            const int r0 = base + rr;                        // C/D: row=(l>>4)*4+v, col=l&15
            const float v0 = ((zmask >> (rr & 31)) & 1u) ? 0.f : acc0[v] + bo;
            const float v1 = ((zmask >> ((rr + 16) & 31)) & 1u) ? 0.f : acc1[v] + bo;
            out[(size_t)r0 * COUT + col0 + lo]        = v0;
            out[(size_t)(r0 + 16) * COUT + col0 + lo] = v1;
        }
        __builtin_amdgcn_sched_barrier(0);  // consume stays below the GEMM

        // ---- phase 3: CONSUME gathers, write next A buffer ----
        if (i < 3)
            build_compute(n, oct, &Abuf[(i + 1) & 1][bf * LDA]);
        __syncthreads();  // next GEMM needs all writes; prev buffer now reusable
    }
}

// fallback (ws too small): fp32 gather, bf16 MFMA, old weight layout
__global__ __launch_bounds__(256, 4)
void meshconv_ref(const float* __restrict__ feat,
                  const int* __restrict__ ring,
                  const unsigned short* __restrict__ wbt,
                  const float* __restrict__ bias,
                  float* __restrict__ out)
{
#define RMBLK 32
#define RLDF 520
    __shared__ unsigned short fcv[RMBLK * RLDF];
    __shared__ int ridx[RMBLK * 6];

    const int t = threadIdx.x;
    const int bid = (blockIdx.x & 7) * (4096 / 8) + (blockIdx.x >> 3);
    const int base = bid * RMBLK;
    const int batch = base >> 14;

    for (int i = t; i < RMBLK * 6; i += 256)
        ridx[i] = ring[(size_t)base * 6 + i];
    __syncthreads();

    {
        const int c2 = t & 63;
        const int fq = t >> 6;
        const float2* fb = (const float2*)feat + (size_t)batch * NFACE * 64;
        for (int it = 0; it < RMBLK / 4; ++it) {
            const int fl = it * 4 + fq;
            const int* ri = &ridx[fl * 6];
            float nl[6], nh[6];
#pragma unroll
            for (int j = 0; j < 6; ++j) {
                float2 u = fb[(size_t)ri[j] * 64 + c2];
                nl[j] = u.x; nh[j] = u.y;
            }
            float fc1l = nl[1] + nl[2] + nl[3] + nl[4] + nl[5];
            float fc1h = nh[1] + nh[2] + nh[3] + nh[4] + nh[5];
            float fc2l = fabsf(5.0f * nl[0] - fc1l);
            float fc2h = fabsf(5.0f * nh[0] - fc1h);
            float fc3l = 0.f, fc3h = 0.f;
#pragma unroll
            for (int a = 1; a < 5; ++a)
#pragma unroll
                for (int b = a + 1; b < 6; ++b) {
                    fc3l += fabsf(nl[a] - nl[b]);
                    fc3h += fabsf(nh[a] - nh[b]);
                }
            unsigned* row = (unsigned*)&fcv[fl * RLDF];
            row[c2]       = pack2bf(nl[0], nh[0]);
            row[64 + c2]  = pack2bf(fc1l, fc1h);
            row[128 + c2] = pack2bf(fc2l, fc2h);
            row[192 + c2] = pack2bf(fc3l, fc3h);
        }
    }
    __syncthreads();

    const int w  = t >> 6;
    const int l  = t & 63;
    const int lo = l & 15;
    const int hi = l >> 4;
    const int col0 = w * 32;

    f32x4 acc[2][2];
#pragma unroll
    for (int rt = 0; rt < 2; ++rt)
#pragma unroll
        for (int ct = 0; ct < 2; ++ct)
            acc[rt][ct] = (f32x4){0.f, 0.f, 0.f, 0.f};

    const unsigned short* __restrict__ wb0 = wbt + (size_t)(col0 + lo) * KGEMM;

    for (int ks = 0; ks < 16; ++ks) {
        const int k0 = ks * 32 + hi * 8;
        short8 a0 = *(const short8*)&fcv[(0 * 16 + lo) * RLDF + k0];
        short8 a1 = *(const short8*)&fcv[(1 * 16 + lo) * RLDF + k0];
        short8 b0 = *(const short8*)&wb0[k0];
        short8 b1 = *(const short8*)&wb0[16 * KGEMM + k0];
        acc[0][0] = __builtin_amdgcn_mfma_f32_16x16x32_bf16(a0, b0, acc[0][0], 0, 0, 0);
        acc[1][0] = __builtin_amdgcn_mfma_f32_16x16x32_bf16(a1, b0, acc[1][0], 0, 0, 0);
        acc[0][1] = __builtin_amdgcn_mfma_f32_16x16x32_bf16(a0, b1, acc[0][1], 0, 0, 0);
        acc[1][1] = __builtin_amdgcn_mfma_f32_16x16x32_bf16(a1, b1, acc[1][1], 0, 0, 0);
    }

    const float bo0 = bias[col0 + lo];
    const float bo1 = bias[col0 + 16 + lo];
#pragma unroll
    for (int rt = 0; rt < 2; ++rt) {
#pragma unroll
        for (int v = 0; v < 4; ++v) {
            const int r = base + rt * 16 + hi * 4 + v;
            out[(size_t)r * COUT + col0 + lo]      = acc[rt][0][v] + bo0;
            out[(size_t)r * COUT + col0 + 16 + lo] = acc[rt][1][v] + bo1;
        }
    }
}

__global__ void zero_kernel(const int* __restrict__ zm, const int* __restrict__ zf,
                            float* __restrict__ out) {
    const int i = blockIdx.x;
    const size_t face = (size_t)zm[i] * NFACE + zf[i];
    out[face * COUT + threadIdx.x] = 0.0f;
}

extern "C" void kernel_launch(void* const* d_in, const int* in_sizes, int n_in,
                              void* d_out, int out_size, void* d_ws, size_t ws_size,
                              hipStream_t stream) {
    const float* feat = (const float*)d_in[0];
    const int*   ring = (const int*)d_in[1];
    const float* wgt  = (const float*)d_in[2];
    const float* bias = (const float*)d_in[3];
    const int*   zm   = (const int*)d_in[4];
    const int*   zf   = (const int*)d_in[5];
    float* out = (float*)d_out;

    const size_t feath_bytes = (size_t)NBATCH * NFACE * CIN * 2;  // 32 MiB
    const size_t wbt_bytes = (size_t)COUT * KGEMM * 2;            // 128 KiB
    const size_t zbm_bytes = ZBM_WORDS * 4;                       // 16 KiB
    const bool use_f16 = ws_size >= feath_bytes + wbt_bytes + zbm_bytes;

    if (use_f16) {
        unsigned* feath = (unsigned*)d_ws;
        _Float16* wbth = (_Float16*)((char*)d_ws + feath_bytes);
        unsigned* zbm = (unsigned*)((char*)d_ws + feath_bytes + wbt_bytes);
        const int wblocks = (COUT * CIN + 255) / 256;  // 64
        hipLaunchKernelGGL(prep_kernel, dim3(FCONV_BLOCKS + wblocks + 1), dim3(256), 0, stream,
                           feat, feath, wgt, wbth, zm, zf, zbm, wblocks);
        hipLaunchKernelGGL(meshconv_v18, dim3(GRID), dim3(512), 0, stream,
                           feath, ring, wbth, bias, zbm, out);
    } else {
        unsigned short* wbt = (unsigned short*)d_ws;
        hipLaunchKernelGGL(wconv_kernel, dim3((COUT * CIN + 255) / 256), dim3(256), 0, stream,
                           wgt, wbt);
        hipLaunchKernelGGL(meshconv_ref, dim3(4096), dim3(256), 0, stream,
                           feat, ring, wbt, bias, out);
        hipLaunchKernelGGL(zero_kernel, dim3(1024), dim3(128), 0, stream, zm, zf, out);
    }
}

// Round 19
// 60.291 us; speedup vs baseline: 1.0343x; 1.0343x over previous
//
#include <hip/hip_runtime.h>
#include <hip/hip_bf16.h>

typedef __attribute__((ext_vector_type(8))) short short8;
typedef __attribute__((ext_vector_type(8))) _Float16 half8;
typedef __attribute__((ext_vector_type(2))) _Float16 h2;
typedef __attribute__((ext_vector_type(4))) float f32x4;
typedef __attribute__((ext_vector_type(4))) unsigned uintx4;

#define NFACE 16384
#define NBATCH 8
#define CIN 128
#define COUT 128
#define KGEMM 512
#define MBLK 128                       // faces per block (4 iters of 32)
#define GRID ((NBATCH * NFACE) / MBLK) // 1024, divisible by 8
#define LDA 520                        // A row stride in halfs (512 + 8) — R15 proven
#define FCONV_BLOCKS 8192              // feature-convert blocks (exact, no bound check)

__device__ __forceinline__ unsigned short f2bf(float x) {
    union { float f; unsigned u; } v; v.f = x;
    unsigned r = v.u + 0x7fffu + ((v.u >> 16) & 1u);  // RNE
    return (unsigned short)(r >> 16);
}
__device__ __forceinline__ unsigned pack2bf(float lo, float hi) {
    return (unsigned)f2bf(lo) | ((unsigned)f2bf(hi) << 16);
}
__device__ __forceinline__ h2 habs2(h2 x) {
    union { h2 h; unsigned u; } v; v.h = x; v.u &= 0x7fff7fffu; return v.h;
}
__device__ __forceinline__ unsigned h2u(h2 x) {
    union { h2 h; unsigned u; } v; v.h = x; return v.u;
}
__device__ __forceinline__ h2 u2h(unsigned x) {
    union { h2 h; unsigned u; } v; v.u = x; return v.h;
}

// ---- fused prep: features fp32 -> f16 (blocks < 8192) + weight fp32 -> f16
// kk-major (blocks >= 8192). R18's zero-bitmap fusion reverted (epilogue tax
// 52.4->54.3 us outweighed the saved launch).
__global__ void prep_kernel(const float* __restrict__ f, unsigned* __restrict__ o,
                            const float* __restrict__ w, _Float16* __restrict__ bt) {
    const int b = blockIdx.x;
    if (b < FCONV_BLOCKS) {
        const int i = b * 256 + threadIdx.x;  // one uint4 (8 floats -> 8 halfs)
        const float4* fp = (const float4*)f;
        float4 a = fp[i * 2], c = fp[i * 2 + 1];
        h2 p0 = {(_Float16)a.x, (_Float16)a.y};
        h2 p1 = {(_Float16)a.z, (_Float16)a.w};
        h2 p2 = {(_Float16)c.x, (_Float16)c.y};
        h2 p3 = {(_Float16)c.z, (_Float16)c.w};
        uint4 r; r.x = h2u(p0); r.y = h2u(p1); r.z = h2u(p2); r.w = h2u(p3);
        ((uint4*)o)[i] = r;
    } else {
        const int i = (b - FCONV_BLOCKS) * 256 + threadIdx.x;  // one (o,c) pair
        if (i >= COUT * CIN) return;
        int oo = i >> 7, c = i & 127;
        float4 wv = ((const float4*)w)[i];
        _Float16* dst = bt + (size_t)oo * KGEMM + c;   // wbth[o][kk*128 + c]
        dst[0]   = (_Float16)wv.x;
        dst[128] = (_Float16)wv.y;
        dst[256] = (_Float16)wv.z;
        dst[384] = (_Float16)wv.w;
    }
}

// ---- old-layout bf16 weight (fallback path): bt[o][kk*128+c] ----
__global__ void wconv_kernel(const float* __restrict__ w, unsigned short* __restrict__ bt) {
    int i = blockIdx.x * 256 + threadIdx.x;
    if (i >= COUT * CIN) return;
    int o = i >> 7, c = i & 127;
#pragma unroll
    for (int kk = 0; kk < 4; ++kk)
        bt[o * KGEMM + kk * CIN + c] = f2bf(w[(o * CIN + c) * 4 + kk]);
}

// Compute fcv from 6 gathered row-segments and write the 4 kk-major A slices.
// (Consume-side of the T14 split — the loads were issued BEFORE the GEMM.)
__device__ __forceinline__ void build_compute(const uint4 n[6], int oct,
                                              _Float16* __restrict__ Arow) {
    unsigned f1w[4], f2w[4], f3w[4];
#pragma unroll
    for (int q = 0; q < 4; ++q) {  // q = word = channels 2q,2q+1
        h2 x0 = u2h(((const unsigned*)&n[0])[q]);
        h2 x1 = u2h(((const unsigned*)&n[1])[q]);
        h2 x2 = u2h(((const unsigned*)&n[2])[q]);
        h2 x3 = u2h(((const unsigned*)&n[3])[q]);
        h2 x4 = u2h(((const unsigned*)&n[4])[q]);
        h2 x5 = u2h(((const unsigned*)&n[5])[q]);
        h2 s = x1 + x2; s = s + x3; s = s + x4; s = s + x5;
        h2 five = {(_Float16)5.0f, (_Float16)5.0f};
        h2 d = habs2(five * x0 - s);
        h2 t3 = habs2(x1 - x2) + habs2(x1 - x3);
        t3 = t3 + habs2(x1 - x4); t3 = t3 + habs2(x1 - x5);
        t3 = t3 + habs2(x2 - x3); t3 = t3 + habs2(x2 - x4);
        t3 = t3 + habs2(x2 - x5); t3 = t3 + habs2(x3 - x4);
        t3 = t3 + habs2(x3 - x5); t3 = t3 + habs2(x4 - x5);
        f1w[q] = h2u(s); f2w[q] = h2u(d); f3w[q] = h2u(t3);
    }
    // A-row layout: halfs [kk*128 + c], c = oct*8 .. +8
    *(uint4*)&Arow[0 * 128 + oct * 8] = n[0];
    *(uint4*)&Arow[1 * 128 + oct * 8] = (uint4){f1w[0], f1w[1], f1w[2], f1w[3]};
    *(uint4*)&Arow[2 * 128 + oct * 8] = (uint4){f2w[0], f2w[1], f2w[2], f2w[3]};
    *(uint4*)&Arow[3 * 128 + oct * 8] = (uint4){f3w[0], f3w[1], f3w[2], f3w[3]};
}

// v19 = R17 exactly (measured best, 60.3 us total): T14 async split, pinned
// 16-col B (on-chip via asm pin), +8-pad A LDS, T5 setprio, fused prep,
// separate zero_kernel. Eleven structural variants pin 50-54 us meshconv;
// binder is the divergent-gather latency chain at the coinciding 16-wave
// VGPR/LDS residency cap — not a pipe roofline any decomposition moves.
__global__ __launch_bounds__(512, 4)
void meshconv_v19(const unsigned* __restrict__ featf16,
                  const int* __restrict__ ring,
                  const _Float16* __restrict__ wbth,
                  const float* __restrict__ bias,
                  float* __restrict__ out)
{
    __shared__ _Float16 Abuf[2][32 * LDA];  // 2 x 32.5 KiB
    __shared__ int ridx[MBLK * 6];          // 3 KiB

    const int t = threadIdx.x;
    // batch-per-XCD swizzle (meshconv-side only — proven good since R4)
    const int bid = (blockIdx.x & 7) * (GRID / 8) + (blockIdx.x >> 3);
    const int base = bid * MBLK;
    const int batch = bid >> 7;

    if (t < 192)  // 128 faces * 6 ints = 192 uint4
        ((uint4*)ridx)[t] = ((const uint4*)(ring + (size_t)base * 6))[t];

    // GEMM mapping: 8 waves x 16 cols each
    const int w  = t >> 6;
    const int l  = t & 63;
    const int lo = l & 15;
    const int hi = l >> 4;
    const int col0 = w * 16;

    // ---- B preload: full K for this wave's 16 cols, once (L2), then PIN ----
    uintx4 B[16];
    {
        const _Float16* wb = wbth + (size_t)(col0 + lo) * KGEMM + hi * 8;
#pragma unroll
        for (int ks = 0; ks < 16; ++ks)
            B[ks] = *(const uintx4*)&wb[ks * 32];
    }
#pragma unroll
    for (int ks = 0; ks < 16; ++ks)
        asm volatile("" : "+v"(B[ks]));   // keep B on-chip (VGPR/AGPR)

    const float bo = bias[col0 + lo];

    // build mapping: thread = (face bf = t>>4 within 32, channel-octet oct = t&15)
    const int bf  = t >> 4;
    const int oct = t & 15;
    const char* __restrict__ fbb = (const char*)featf16 + (size_t)batch * NFACE * 256;

    __syncthreads();  // ridx ready

    // prologue: tile 0 built in place
    {
        uint4 n[6];
        const int* ri = &ridx[bf * 6];
#pragma unroll
        for (int j = 0; j < 6; ++j)
            n[j] = *(const uint4*)(fbb + (size_t)(ri[j] * 256 + oct * 16));
        build_compute(n, oct, &Abuf[0][bf * LDA]);
    }
    __syncthreads();

    for (int i = 0; i < 4; ++i) {
        // ---- phase 1: ISSUE next tile's gathers (held across GEMM) ----
        uint4 n[6];
        if (i < 3) {
            const int* ri = &ridx[((i + 1) * 32 + bf) * 6];
#pragma unroll
            for (int j = 0; j < 6; ++j)
                n[j] = *(const uint4*)(fbb + (size_t)(ri[j] * 256 + oct * 16));
        }
        __builtin_amdgcn_sched_barrier(0);  // loads stay issued here

        // ---- phase 2: GEMM on Abuf[i&1] (hides gather latency), T5 setprio ----
        f32x4 acc0 = (f32x4){0.f, 0.f, 0.f, 0.f};
        f32x4 acc1 = (f32x4){0.f, 0.f, 0.f, 0.f};
        const _Float16* __restrict__ Ab = &Abuf[i & 1][0];
        __builtin_amdgcn_s_setprio(1);
#pragma unroll
        for (int ks = 0; ks < 16; ++ks) {
            const int k0 = ks * 32 + hi * 8;
            half8 a0 = *(const half8*)&Ab[lo * LDA + k0];
            half8 a1 = *(const half8*)&Ab[(16 + lo) * LDA + k0];
            half8 b = __builtin_bit_cast(half8, B[ks]);
            acc0 = __builtin_amdgcn_mfma_f32_16x16x32_f16(a0, b, acc0, 0, 0, 0);
            acc1 = __builtin_amdgcn_mfma_f32_16x16x32_f16(a1, b, acc1, 0, 0, 0);
        }
        __builtin_amdgcn_s_setprio(0);
#pragma unroll
        for (int v = 0; v < 4; ++v) {
            const int r0 = base + i * 32 + hi * 4 + v;       // C/D: row=(l>>4)*4+v, col=l&15
            out[(size_t)r0 * COUT + col0 + lo]        = acc0[v] + bo;
            out[(size_t)(r0 + 16) * COUT + col0 + lo] = acc1[v] + bo;
        }
        __builtin_amdgcn_sched_barrier(0);  // consume stays below the GEMM

        // ---- phase 3: CONSUME gathers, write next A buffer ----
        if (i < 3)
            build_compute(n, oct, &Abuf[(i + 1) & 1][bf * LDA]);
        __syncthreads();  // next GEMM needs all writes; prev buffer now reusable
    }
}

// fallback (ws too small): fp32 gather, bf16 MFMA, old weight layout
__global__ __launch_bounds__(256, 4)
void meshconv_ref(const float* __restrict__ feat,
                  const int* __restrict__ ring,
                  const unsigned short* __restrict__ wbt,
                  const float* __restrict__ bias,
                  float* __restrict__ out)
{
#define RMBLK 32
#define RLDF 520
    __shared__ unsigned short fcv[RMBLK * RLDF];
    __shared__ int ridx[RMBLK * 6];

    const int t = threadIdx.x;
    const int bid = (blockIdx.x & 7) * (4096 / 8) + (blockIdx.x >> 3);
    const int base = bid * RMBLK;
    const int batch = base >> 14;

    for (int i = t; i < RMBLK * 6; i += 256)
        ridx[i] = ring[(size_t)base * 6 + i];
    __syncthreads();

    {
        const int c2 = t & 63;
        const int fq = t >> 6;
        const float2* fb = (const float2*)feat + (size_t)batch * NFACE * 64;
        for (int it = 0; it < RMBLK / 4; ++it) {
            const int fl = it * 4 + fq;
            const int* ri = &ridx[fl * 6];
            float nl[6], nh[6];
#pragma unroll
            for (int j = 0; j < 6; ++j) {
                float2 u = fb[(size_t)ri[j] * 64 + c2];
                nl[j] = u.x; nh[j] = u.y;
            }
            float fc1l = nl[1] + nl[2] + nl[3] + nl[4] + nl[5];
            float fc1h = nh[1] + nh[2] + nh[3] + nh[4] + nh[5];
            float fc2l = fabsf(5.0f * nl[0] - fc1l);
            float fc2h = fabsf(5.0f * nh[0] - fc1h);
            float fc3l = 0.f, fc3h = 0.f;
#pragma unroll
            for (int a = 1; a < 5; ++a)
#pragma unroll
                for (int b = a + 1; b < 6; ++b) {
                    fc3l += fabsf(nl[a] - nl[b]);
                    fc3h += fabsf(nh[a] - nh[b]);
                }
            unsigned* row = (unsigned*)&fcv[fl * RLDF];
            row[c2]       = pack2bf(nl[0], nh[0]);
            row[64 + c2]  = pack2bf(fc1l, fc1h);
            row[128 + c2] = pack2bf(fc2l, fc2h);
            row[192 + c2] = pack2bf(fc3l, fc3h);
        }
    }
    __syncthreads();

    const int w  = t >> 6;
    const int l  = t & 63;
    const int lo = l & 15;
    const int hi = l >> 4;
    const int col0 = w * 32;

    f32x4 acc[2][2];
#pragma unroll
    for (int rt = 0; rt < 2; ++rt)
#pragma unroll
        for (int ct = 0; ct < 2; ++ct)
            acc[rt][ct] = (f32x4){0.f, 0.f, 0.f, 0.f};

    const unsigned short* __restrict__ wb0 = wbt + (size_t)(col0 + lo) * KGEMM;

    for (int ks = 0; ks < 16; ++ks) {
        const int k0 = ks * 32 + hi * 8;
        short8 a0 = *(const short8*)&fcv[(0 * 16 + lo) * RLDF + k0];
        short8 a1 = *(const short8*)&fcv[(1 * 16 + lo) * RLDF + k0];
        short8 b0 = *(const short8*)&wb0[k0];
        short8 b1 = *(const short8*)&wb0[16 * KGEMM + k0];
        acc[0][0] = __builtin_amdgcn_mfma_f32_16x16x32_bf16(a0, b0, acc[0][0], 0, 0, 0);
        acc[1][0] = __builtin_amdgcn_mfma_f32_16x16x32_bf16(a1, b0, acc[1][0], 0, 0, 0);
        acc[0][1] = __builtin_amdgcn_mfma_f32_16x16x32_bf16(a0, b1, acc[0][1], 0, 0, 0);
        acc[1][1] = __builtin_amdgcn_mfma_f32_16x16x32_bf16(a1, b1, acc[1][1], 0, 0, 0);
    }

    const float bo0 = bias[col0 + lo];
    const float bo1 = bias[col0 + 16 + lo];
#pragma unroll
    for (int rt = 0; rt < 2; ++rt) {
#pragma unroll
        for (int v = 0; v < 4; ++v) {
            const int r = base + rt * 16 + hi * 4 + v;
            out[(size_t)r * COUT + col0 + lo]      = acc[rt][0][v] + bo0;
            out[(size_t)r * COUT + col0 + 16 + lo] = acc[rt][1][v] + bo1;
        }
    }
}

__global__ void zero_kernel(const int* __restrict__ zm, const int* __restrict__ zf,
                            float* __restrict__ out) {
    const int i = blockIdx.x;
    const size_t face = (size_t)zm[i] * NFACE + zf[i];
    out[face * COUT + threadIdx.x] = 0.0f;
}

extern "C" void kernel_launch(void* const* d_in, const int* in_sizes, int n_in,
                              void* d_out, int out_size, void* d_ws, size_t ws_size,
                              hipStream_t stream) {
    const float* feat = (const float*)d_in[0];
    const int*   ring = (const int*)d_in[1];
    const float* wgt  = (const float*)d_in[2];
    const float* bias = (const float*)d_in[3];
    const int*   zm   = (const int*)d_in[4];
    const int*   zf   = (const int*)d_in[5];
    float* out = (float*)d_out;

    const size_t feath_bytes = (size_t)NBATCH * NFACE * CIN * 2;  // 32 MiB
    const size_t wbt_bytes = (size_t)COUT * KGEMM * 2;            // 128 KiB
    const bool use_f16 = ws_size >= feath_bytes + wbt_bytes;

    if (use_f16) {
        unsigned* feath = (unsigned*)d_ws;
        _Float16* wbth = (_Float16*)((char*)d_ws + feath_bytes);
        const int wblocks = (COUT * CIN + 255) / 256;  // 64
        hipLaunchKernelGGL(prep_kernel, dim3(FCONV_BLOCKS + wblocks), dim3(256), 0, stream,
                           feat, feath, wgt, wbth);
        hipLaunchKernelGGL(meshconv_v19, dim3(GRID), dim3(512), 0, stream,
                           feath, ring, wbth, bias, out);
    } else {
        unsigned short* wbt = (unsigned short*)d_ws;
        hipLaunchKernelGGL(wconv_kernel, dim3((COUT * CIN + 255) / 256), dim3(256), 0, stream,
                           wgt, wbt);
        hipLaunchKernelGGL(meshconv_ref, dim3(4096), dim3(256), 0, stream,
                           feat, ring, wbt, bias, out);
    }
    hipLaunchKernelGGL(zero_kernel, dim3(1024), dim3(128), 0, stream, zm, zf, out);
}